// Round 5
// baseline (3839.944 us; speedup 1.0000x reference)
//
#include <hip/hip_runtime.h>
#include <hip/hip_bf16.h>

// Problem constants (fixed by setup_inputs)
constexpr int T_ = 4, B_ = 8, N_ = 1024, C_ = 512, H_ = 8, D_ = 64;
constexpr int M_ = B_ * N_;          // 8192 rows per timestep
constexpr int K_ = 512;
constexpr int MH_ = 4096;            // rows per timestep per half-pass

#define TAU_INV 0.5f
#define V_TH    1.0f
#define BN_EPS  1e-5f

// ---- load 4 consecutive elements as float ---------------------------------
__device__ __forceinline__ void ld4(const float* p, float* d) {
  const float4 v = *(const float4*)p;
  d[0] = v.x; d[1] = v.y; d[2] = v.z; d[3] = v.w;
}
__device__ __forceinline__ void ld4(const __hip_bfloat16* p, float* d) {
  const ushort4 u = *(const ushort4*)p;
  d[0] = __bfloat162float(*(const __hip_bfloat16*)&u.x);
  d[1] = __bfloat162float(*(const __hip_bfloat16*)&u.y);
  d[2] = __bfloat162float(*(const __hip_bfloat16*)&u.z);
  d[3] = __bfloat162float(*(const __hip_bfloat16*)&u.w);
}
// ---- store 4 consecutive values -------------------------------------------
__device__ __forceinline__ void st4(__hip_bfloat16* p, const float* s) {
  ushort4 u;
  *(__hip_bfloat16*)&u.x = __float2bfloat16(s[0]);
  *(__hip_bfloat16*)&u.y = __float2bfloat16(s[1]);
  *(__hip_bfloat16*)&u.z = __float2bfloat16(s[2]);
  *(__hip_bfloat16*)&u.w = __float2bfloat16(s[3]);
  *(ushort4*)p = u;
}
__device__ __forceinline__ void st4(float* p, const float* s) {
  *(float4*)p = make_float4(s[0], s[1], s[2], s[3]);
}

// ---------------------------------------------------------------------------
// GEMM (+bias +BN eval) -> fp32 Y.
// BIT-EXACTNESS CONTRACT: each output's k-summation is a single fp32
// accumulator over k = 0..511 STRICTLY ASCENDING; bias/BN expressions are
// textually identical to the rounds that matched the reference at absmax 0.0.
//
// Tile 128 rows x 256 cols, 256 threads, 8x16 outputs/thread. BK=16 (25KB
// LDS -> 3 blocks/CU with launch_bounds(256,3)).
// LDS is k-major with XOR swizzle: element (kk, m) lives at column
//   col' = ((m>>2) ^ (kk>>3))*4 + (m&3),  row strides 132 / 260 (== 4 mod 32)
// => staging transpose-writes are 2-way (free), hot-loop b128 reads
// conflict-free with 2 precomputed base pointers per operand.
//
// Row index r is the flattened (t, mh) pair: t = r >> RSHIFT, mh = r & mask.
// Global A row = t*M_ + half_base + mh  (half_base in elements of rows).
// ---------------------------------------------------------------------------
template <typename TIn> struct GemmArgs {
  const TIn* A;
  const float* W[3];
  const float* bias[3];
  const float* bn[3];
  float* Y[3];
  int half_base;           // 0 or MH_ (row offset within a timestep)
};

template <int RSHIFT, typename TIn>
__global__ __launch_bounds__(256, 3) void gemm_bn(GemmArgs<TIn> args)
{
  constexpr int BK = 16;
  constexpr int RMASK = (1 << RSHIFT) - 1;
  __shared__ __align__(16) float AsF[BK * 132];
  __shared__ __align__(16) float BsF[BK * 260];

  const int w = blockIdx.z;
  const TIn*   __restrict__ A    = args.A;
  const float* __restrict__ W    = args.W[w];
  const float* __restrict__ bias = args.bias[w];
  const float* __restrict__ bnp  = args.bn[w];
  float*       __restrict__ Y    = args.Y[w];
  const int halfb = args.half_base;

  const int tid = threadIdx.x;
  const int tx = tid & 15, ty = tid >> 4;
  const int bm = blockIdx.y * 128;      // flattened (t, mh) row base
  const int bn0 = blockIdx.x * 256;

  // Hot-loop read base pointers (swizzle variants s=0,1)
  const float* Ard[2] = { AsF + (ty ^ 0) * 4, AsF + (ty ^ 1) * 4 };
  const float* Brd[2] = { BsF + (tx ^ 0) * 4, BsF + (tx ^ 1) * 4 };

  float acc[2][4][4][4];   // [rowgrp g][colgrp h][row i][col j]
#pragma unroll
  for (int g = 0; g < 2; ++g)
#pragma unroll
    for (int h = 0; h < 4; ++h)
#pragma unroll
      for (int i = 0; i < 4; ++i)
#pragma unroll
        for (int j = 0; j < 4; ++j) acc[g][h][i][j] = 0.0f;

  for (int k0 = 0; k0 < K_; k0 += BK) {
    // ---- stage A tile (128 x 16), swizzled k-major ----------------------
#pragma unroll
    for (int i = 0; i < 2; ++i) {
      const int idx = tid + 256 * i;            // < 512 float4s
      const int m = idx >> 2, q = idx & 3;
      const int r = bm + m;
      const size_t arow = (size_t)(r >> RSHIFT) * M_ + halfb + (r & RMASK);
      float tmp[4];
      ld4(&A[arow * K_ + k0 + q * 4], tmp);
      const int colb = (((m >> 2) ^ (q >> 1)) << 2) + (m & 3);
#pragma unroll
      for (int j = 0; j < 4; ++j) AsF[(4 * q + j) * 132 + colb] = tmp[j];
    }
    // ---- stage B tile (256 x 16 from W row-major), swizzled -------------
#pragma unroll
    for (int i = 0; i < 4; ++i) {
      const int idx = tid + 256 * i;            // < 1024 float4s
      const int n = idx >> 2, q = idx & 3;
      float tmp[4];
      ld4(&W[(size_t)(bn0 + n) * K_ + k0 + q * 4], tmp);
      const int colb = (((n >> 2) ^ (q >> 1)) << 2) + (n & 3);
#pragma unroll
      for (int j = 0; j < 4; ++j) BsF[(4 * q + j) * 260 + colb] = tmp[j];
    }
    __syncthreads();

    // ---- hot loop: k strictly ascending ---------------------------------
#pragma unroll
    for (int kk = 0; kk < BK; ++kk) {
      const int s = kk >> 3;                    // compile-time per unrolled kk
      float a[2][4], b[4][4];
#pragma unroll
      for (int g = 0; g < 2; ++g)
        ld4(Ard[s] + kk * 132 + 64 * g, a[g]);
#pragma unroll
      for (int h = 0; h < 4; ++h)
        ld4(Brd[s] + kk * 260 + 64 * h, b[h]);
#pragma unroll
      for (int g = 0; g < 2; ++g)
#pragma unroll
        for (int h = 0; h < 4; ++h)
#pragma unroll
          for (int i = 0; i < 4; ++i)
#pragma unroll
            for (int j = 0; j < 4; ++j)
              acc[g][h][i][j] += a[g][i] * b[h][j];
    }
    __syncthreads();
  }

  // ---- epilogue: bias -> BN (identical expressions), store fp32 y --------
#pragma unroll
  for (int h = 0; h < 4; ++h) {
    const int d = bn0 + tx * 4 + h * 64;
    float bi[4], gg[4], be[4], mu[4], vv[4];
    ld4(&bias[d], bi);
    ld4(&bnp[d], gg);
    ld4(&bnp[C_ + d], be);
    ld4(&bnp[2 * C_ + d], mu);
    ld4(&bnp[3 * C_ + d], vv);
    float inv[4];
#pragma unroll
    for (int j = 0; j < 4; ++j) inv[j] = 1.0f / sqrtf(vv[j] + BN_EPS);
#pragma unroll
    for (int g = 0; g < 2; ++g)
#pragma unroll
      for (int i = 0; i < 4; ++i) {
        const int r = bm + ty * 4 + g * 64 + i;
        float sv[4];
#pragma unroll
        for (int j = 0; j < 4; ++j) {
          float y = acc[g][h][i][j] + bi[j];
          y = (y - mu[j]) * inv[j] * gg[j] + be[j];
          sv[j] = y;
        }
        st4(&Y[(size_t)r * C_ + d], sv);
      }
  }
}

// ---------------------------------------------------------------------------
// Triple LIF scan over a half-pass: Yh[w][t][NH] fp32 -> spikes (bf16) into
// the full (T, M, C) spike buffers at row offset half_base.
// Identical update expressions as all prior rounds (absmax 0.0).
// ---------------------------------------------------------------------------
struct Lif3Args { __hip_bfloat16* S[3]; };

__global__ __launch_bounds__(256) void lif3_scan(
    const float* __restrict__ Yh, Lif3Args args, size_t half_elem_base)
{
  const size_t NH = (size_t)MH_ * C_;          // 2,097,152 elems per (w,t)
  const size_t npt = (size_t)M_ * C_;
  const size_t e4 = ((size_t)blockIdx.x * 256 + threadIdx.x) * 4;
  if (e4 >= NH) return;
#pragma unroll
  for (int w = 0; w < 3; ++w) {
    __hip_bfloat16* __restrict__ S = args.S[w];
    const float* __restrict__ Yw = Yh + (size_t)w * T_ * NH;
    float mem[4] = {0.0f, 0.0f, 0.0f, 0.0f};
#pragma unroll
    for (int t = 0; t < T_; ++t) {
      float y[4], sv[4];
      ld4(&Yw[(size_t)t * NH + e4], y);
#pragma unroll
      for (int j = 0; j < 4; ++j) {
        float m2 = mem[j] + (y[j] - mem[j]) * TAU_INV;
        float s = (m2 - V_TH >= 0.0f) ? 1.0f : 0.0f;
        sv[j] = s;
        mem[j] = (s != 0.0f) ? 0.0f : m2;
      }
      st4(&S[(size_t)t * npt + half_elem_base + e4], sv);
    }
  }
}

// ---------------------------------------------------------------------------
// Single LIF scan: Y (T, M*C) fp32 -> spikes (T, M*C).
// ---------------------------------------------------------------------------
template <typename TOut>
__global__ __launch_bounds__(256) void lif_scan(
    const float* __restrict__ Y, TOut* __restrict__ S)
{
  const size_t npt = (size_t)M_ * C_;
  const size_t idx4 = ((size_t)blockIdx.x * 256 + threadIdx.x) * 4;
  if (idx4 >= npt) return;
  float mem[4] = {0.0f, 0.0f, 0.0f, 0.0f};
#pragma unroll
  for (int t = 0; t < T_; ++t) {
    float y[4], sv[4];
    ld4(&Y[(size_t)t * npt + idx4], y);
#pragma unroll
    for (int j = 0; j < 4; ++j) {
      float m2 = mem[j] + (y[j] - mem[j]) * TAU_INV;
      float s = (m2 - V_TH >= 0.0f) ? 1.0f : 0.0f;
      sv[j] = s;
      mem[j] = (s != 0.0f) ? 0.0f : m2;
    }
    st4(&S[(size_t)t * npt + idx4], sv);
  }
}

// ---------------------------------------------------------------------------
// Linear attention per (t,b,h): kv = k^T v / N (64x64), y = q @ kv (1024x64).
// Spikes are {0,1}: kv entries are counts/1024 and y sums <=64 multiples of
// 2^-10 -> all arithmetic here is EXACT in fp32 regardless of order.
// ---------------------------------------------------------------------------
__global__ __launch_bounds__(256) void attn_kernel(
    const __hip_bfloat16* __restrict__ Q,
    const __hip_bfloat16* __restrict__ Kk,
    const __hip_bfloat16* __restrict__ V,
    float* __restrict__ Y)
{
  __shared__ float s1[64][65];
  __shared__ float s2[64][65];
  __shared__ float kv[64][65];
  const int tid = threadIdx.x;
  const int h = blockIdx.x, b = blockIdx.y, t = blockIdx.z;
  const size_t base = ((size_t)t * B_ + b) * (size_t)N_ * C_ + (size_t)h * D_;
  const int d0 = (tid >> 4) * 4;
  const int e0 = (tid & 15) * 4;

  float acc[4][4];
#pragma unroll
  for (int i = 0; i < 4; ++i)
#pragma unroll
    for (int j = 0; j < 4; ++j) acc[i][j] = 0.0f;

  for (int nc = 0; nc < N_; nc += 64) {
#pragma unroll
    for (int i = 0; i < 16; ++i) {
      int idx = tid + i * 256;
      int r = idx >> 6, c = idx & 63;
      s1[r][c] = __bfloat162float(Kk[base + (size_t)(nc + r) * C_ + c]);
      s2[r][c] = __bfloat162float(V[base + (size_t)(nc + r) * C_ + c]);
    }
    __syncthreads();
#pragma unroll
    for (int nn = 0; nn < 64; ++nn) {
      float a[4], bb[4];
#pragma unroll
      for (int i = 0; i < 4; ++i) a[i] = s1[nn][d0 + i];
#pragma unroll
      for (int j = 0; j < 4; ++j) bb[j] = s2[nn][e0 + j];
#pragma unroll
      for (int i = 0; i < 4; ++i)
#pragma unroll
        for (int j = 0; j < 4; ++j) acc[i][j] += a[i] * bb[j];
    }
    __syncthreads();
  }
#pragma unroll
  for (int i = 0; i < 4; ++i)
#pragma unroll
    for (int j = 0; j < 4; ++j)
      kv[d0 + i][e0 + j] = acc[i][j] * (1.0f / (float)N_);
  __syncthreads();

  for (int rc = 0; rc < N_; rc += 64) {
#pragma unroll
    for (int i = 0; i < 16; ++i) {
      int idx = tid + i * 256;
      int r = idx >> 6, c = idx & 63;
      s1[r][c] = __bfloat162float(Q[base + (size_t)(rc + r) * C_ + c]);
    }
    __syncthreads();
    float o[4][4];
#pragma unroll
    for (int i = 0; i < 4; ++i)
#pragma unroll
      for (int j = 0; j < 4; ++j) o[i][j] = 0.0f;
#pragma unroll
    for (int d = 0; d < 64; ++d) {
      float a[4], bb[4];
#pragma unroll
      for (int i = 0; i < 4; ++i) a[i] = s1[d0 + i][d];
#pragma unroll
      for (int j = 0; j < 4; ++j) bb[j] = kv[d][e0 + j];
#pragma unroll
      for (int i = 0; i < 4; ++i)
#pragma unroll
        for (int j = 0; j < 4; ++j) o[i][j] += a[i] * bb[j];
    }
#pragma unroll
    for (int i = 0; i < 4; ++i)
#pragma unroll
      for (int j = 0; j < 4; ++j)
        Y[base + (size_t)(rc + d0 + i) * C_ + e0 + j] = o[i][j];
    __syncthreads();
  }
}

extern "C" void kernel_launch(void* const* d_in, const int* in_sizes, int n_in,
                              void* d_out, int out_size, void* d_ws, size_t ws_size,
                              hipStream_t stream)
{
  const float* x   = (const float*)d_in[0];
  const float* Wq  = (const float*)d_in[1];
  const float* bq  = (const float*)d_in[2];
  const float* Wk  = (const float*)d_in[3];
  const float* bk  = (const float*)d_in[4];
  const float* Wv  = (const float*)d_in[5];
  const float* bv  = (const float*)d_in[6];
  const float* Wp  = (const float*)d_in[7];
  const float* bp  = (const float*)d_in[8];
  const float* bnp = (const float*)d_in[9];   // (4 layers, 4, C)
  float* out = (float*)d_out;

  char* ws = (char*)d_ws;
  const size_t nElem = (size_t)T_ * M_ * C_;           // 16,777,216
  const size_t NHT   = (size_t)T_ * MH_ * C_;          //  8,388,608 per weight
  float*          Yh  = (float*)ws;          ws += 3 * NHT * sizeof(float);  // 100.7MB
  __hip_bfloat16* q_s = (__hip_bfloat16*)ws; ws += nElem * sizeof(__hip_bfloat16);
  __hip_bfloat16* k_s = (__hip_bfloat16*)ws; ws += nElem * sizeof(__hip_bfloat16);
  __hip_bfloat16* v_s = (__hip_bfloat16*)ws; ws += nElem * sizeof(__hip_bfloat16);
  __hip_bfloat16* a_s = (__hip_bfloat16*)ws; ws += nElem * sizeof(__hip_bfloat16);
  float* Yfull = (float*)Yh;   // alias: Yh dead after lif3 of half 1

  GemmArgs<float> qa;
  qa.A = x;
  qa.W[0] = Wq; qa.W[1] = Wk; qa.W[2] = Wv;
  qa.bias[0] = bq; qa.bias[1] = bk; qa.bias[2] = bv;
  qa.bn[0] = bnp + 0 * 4 * C_;
  qa.bn[1] = bnp + 1 * 4 * C_;
  qa.bn[2] = bnp + 2 * 4 * C_;
  qa.Y[0] = Yh; qa.Y[1] = Yh + NHT; qa.Y[2] = Yh + 2 * NHT;

  Lif3Args la; la.S[0] = q_s; la.S[1] = k_s; la.S[2] = v_s;

  const dim3 ggq(C_ / 256, (T_ * MH_) / 128, 3);   // (2, 128, 3) = 768 blocks
  const unsigned lif3_grid = (unsigned)(((size_t)MH_ * C_ / 4 + 255) / 256); // 2048
  const unsigned lif_grid  = (unsigned)(((size_t)M_ * C_ / 4 + 255) / 256);  // 4096

  // ---- q,k,v fused GEMM+BN over two row-halves, LIF scan between ---------
  qa.half_base = 0;
  gemm_bn<12, float><<<ggq, 256, 0, stream>>>(qa);
  lif3_scan<<<lif3_grid, 256, 0, stream>>>(Yh, la, 0);

  qa.half_base = MH_;
  gemm_bn<12, float><<<ggq, 256, 0, stream>>>(qa);
  lif3_scan<<<lif3_grid, 256, 0, stream>>>(Yh, la, (size_t)MH_ * C_);

  // ---- attention (exact) -> Yfull, then attn_lif -> a_s ------------------
  attn_kernel<<<dim3(H_, B_, T_), 256, 0, stream>>>(q_s, k_s, v_s, Yfull);
  lif_scan<__hip_bfloat16><<<lif_grid, 256, 0, stream>>>(Yfull, a_s);

  // ---- proj GEMM+BN (full rows) -> Yfull, then proj_lif -> out -----------
  GemmArgs<__hip_bfloat16> pa;
  pa.A = a_s;
  pa.W[0] = Wp;  pa.bias[0] = bp;  pa.bn[0] = bnp + 3 * 4 * C_;
  pa.Y[0] = Yfull;
  pa.half_base = 0;
  gemm_bn<13, __hip_bfloat16><<<dim3(C_ / 256, (T_ * M_) / 128, 1), 256, 0, stream>>>(pa);
  lif_scan<float><<<lif_grid, 256, 0, stream>>>(Yfull, out);
}

// Round 6
// 1131.034 us; speedup vs baseline: 3.3951x; 3.3951x over previous
//
#include <hip/hip_runtime.h>
#include <hip/hip_bf16.h>

// Problem constants (fixed by setup_inputs)
constexpr int T_ = 4, B_ = 8, N_ = 1024, C_ = 512, H_ = 8, D_ = 64;
constexpr int M_ = B_ * N_;          // 8192 rows per timestep
constexpr int MT_ = T_ * M_;         // 32768 rows total (t-flattened)
constexpr int K_ = 512;

#define TAU_INV 0.5f
#define V_TH    1.0f
#define BN_EPS  1e-5f

// ---- load 4 consecutive elements as float ---------------------------------
__device__ __forceinline__ void ld4(const float* p, float* d) {
  const float4 v = *(const float4*)p;
  d[0] = v.x; d[1] = v.y; d[2] = v.z; d[3] = v.w;
}
__device__ __forceinline__ void ld4(const __hip_bfloat16* p, float* d) {
  const ushort4 u = *(const ushort4*)p;
  d[0] = __bfloat162float(*(const __hip_bfloat16*)&u.x);
  d[1] = __bfloat162float(*(const __hip_bfloat16*)&u.y);
  d[2] = __bfloat162float(*(const __hip_bfloat16*)&u.z);
  d[3] = __bfloat162float(*(const __hip_bfloat16*)&u.w);
}
// ---- store 4 consecutive values -------------------------------------------
__device__ __forceinline__ void st4(__hip_bfloat16* p, const float* s) {
  ushort4 u;
  *(__hip_bfloat16*)&u.x = __float2bfloat16(s[0]);
  *(__hip_bfloat16*)&u.y = __float2bfloat16(s[1]);
  *(__hip_bfloat16*)&u.z = __float2bfloat16(s[2]);
  *(__hip_bfloat16*)&u.w = __float2bfloat16(s[3]);
  *(ushort4*)p = u;
}
__device__ __forceinline__ void st4(float* p, const float* s) {
  *(float4*)p = make_float4(s[0], s[1], s[2], s[3]);
}

// ---------------------------------------------------------------------------
// GEMM (+bias +BN eval) over all T*M rows at once -> fp32 Y.
// BIT-EXACTNESS CONTRACT: each output's k-summation is a single fp32
// accumulator over k = 0..511 STRICTLY ASCENDING; bias/BN expressions are
// textually identical to the rounds that matched the reference at absmax 0.0.
//
// Tile: 128 rows x 256 cols, 256 threads, 8x16 outputs/thread, BK=32,
// launch_bounds(256,2)  [R4 config — DO NOT raise to 3: R5 proved it spills].
//
// LDS k-major with XOR granule swizzle: element (kk, m) stored at
//   word = kk*LDA + ((gran(m) ^ (kk>>3)) << 2) + (m&3),   gran(m)=m>>2
// Row strides 132 / 260 (== 4 mod 32):
//  - staging: 4x4 micro-tile register transpose -> ds_write_b128, exactly
//    8 words/bank per wave-write (minimum; conflict-free).
//  - hot loop: A reads 4-granule broadcast; B reads 2 words/bank (free).
// ---------------------------------------------------------------------------
template <typename TIn>
__global__ __launch_bounds__(256, 2) void gemm_bn(
    const TIn* __restrict__ A, const float* __restrict__ W,
    const float* __restrict__ bias, const float* __restrict__ bnp,
    float* __restrict__ Y)
{
  constexpr int BK = 32;
  constexpr int LDA = 132;   // words per k-row of As (== 4 mod 32)
  constexpr int LDB = 260;   // words per k-row of Bs (== 4 mod 32)
  __shared__ __align__(16) float AsF[BK * LDA];
  __shared__ __align__(16) float BsF[BK * LDB];

  const int tid = threadIdx.x;
  const int tx = tid & 15, ty = tid >> 4;
  const int bm = blockIdx.y * 128;
  const int bn0 = blockIdx.x * 256;

  // staging micro-tile assignment: q = k-quad, gm/gn = 4-row granule
  const int sq = tid & 7;          // k-quad 0..7
  const int sg = tid >> 3;         // granule 0..31
  const int sX = sq >> 1;          // swizzle X for kk in this q (== (4q+j)>>3)

  float acc[2][4][4][4];   // [rowgrp g][colgrp h][row i][col j]
#pragma unroll
  for (int g = 0; g < 2; ++g)
#pragma unroll
    for (int h = 0; h < 4; ++h)
#pragma unroll
      for (int i = 0; i < 4; ++i)
#pragma unroll
        for (int j = 0; j < 4; ++j) acc[g][h][i][j] = 0.0f;

  for (int k0 = 0; k0 < K_; k0 += BK) {
    // ---- stage A tile (128 x 32): 1 micro-tile/thread --------------------
    {
      float tmp[4][4];
#pragma unroll
      for (int i = 0; i < 4; ++i)
        ld4(&A[(size_t)(bm + 4 * sg + i) * K_ + k0 + 4 * sq], tmp[i]);
      const int colb = ((sg ^ sX) << 2);
#pragma unroll
      for (int j = 0; j < 4; ++j) {
        float col[4] = { tmp[0][j], tmp[1][j], tmp[2][j], tmp[3][j] };
        st4(&AsF[(4 * sq + j) * LDA + colb], col);
      }
    }
    // ---- stage B tile (256 x 32): 2 micro-tiles/thread -------------------
#pragma unroll
    for (int i2 = 0; i2 < 2; ++i2) {
      const int gn = sg + 32 * i2;
      float tmp[4][4];
#pragma unroll
      for (int i = 0; i < 4; ++i)
        ld4(&W[(size_t)(bn0 + 4 * gn + i) * K_ + k0 + 4 * sq], tmp[i]);
      const int colb = ((gn ^ sX) << 2);
#pragma unroll
      for (int j = 0; j < 4; ++j) {
        float col[4] = { tmp[0][j], tmp[1][j], tmp[2][j], tmp[3][j] };
        st4(&BsF[(4 * sq + j) * LDB + colb], col);
      }
    }
    __syncthreads();

    // ---- hot loop: k strictly ascending ----------------------------------
#pragma unroll
    for (int kk = 0; kk < BK; ++kk) {
      const int Xk = kk >> 3;                    // compile-time after unroll
      float a[2][4], b[4][4];
#pragma unroll
      for (int g = 0; g < 2; ++g)
        ld4(&AsF[kk * LDA + (((ty + 16 * g) ^ Xk) << 2)], a[g]);
#pragma unroll
      for (int h = 0; h < 4; ++h)
        ld4(&BsF[kk * LDB + (((tx + 16 * h) ^ Xk) << 2)], b[h]);
#pragma unroll
      for (int g = 0; g < 2; ++g)
#pragma unroll
        for (int h = 0; h < 4; ++h)
#pragma unroll
          for (int i = 0; i < 4; ++i)
#pragma unroll
            for (int j = 0; j < 4; ++j)
              acc[g][h][i][j] += a[g][i] * b[h][j];
    }
    __syncthreads();
  }

  // ---- epilogue: bias -> BN (identical expressions), store fp32 y --------
#pragma unroll
  for (int h = 0; h < 4; ++h) {
    const int d = bn0 + tx * 4 + h * 64;
    float bi[4], gg[4], be[4], mu[4], vv[4];
    ld4(&bias[d], bi);
    ld4(&bnp[d], gg);
    ld4(&bnp[C_ + d], be);
    ld4(&bnp[2 * C_ + d], mu);
    ld4(&bnp[3 * C_ + d], vv);
    float inv[4];
#pragma unroll
    for (int j = 0; j < 4; ++j) inv[j] = 1.0f / sqrtf(vv[j] + BN_EPS);
#pragma unroll
    for (int g = 0; g < 2; ++g)
#pragma unroll
      for (int i = 0; i < 4; ++i) {
        const int row = bm + ty * 4 + g * 64 + i;
        float sv[4];
#pragma unroll
        for (int j = 0; j < 4; ++j) {
          float y = acc[g][h][i][j] + bi[j];
          y = (y - mu[j]) * inv[j] * gg[j] + be[j];
          sv[j] = y;
        }
        st4(&Y[(size_t)row * C_ + d], sv);
      }
  }
}

// ---------------------------------------------------------------------------
// Multi-step LIF scan: Y (T, M*C) fp32 -> spikes (T, M*C).
// Identical update expressions as all prior rounds (absmax 0.0).
// ---------------------------------------------------------------------------
template <typename TOut>
__global__ __launch_bounds__(256) void lif_scan(
    const float* __restrict__ Y, TOut* __restrict__ S)
{
  const size_t npt = (size_t)M_ * C_;
  const size_t idx4 = ((size_t)blockIdx.x * 256 + threadIdx.x) * 4;
  if (idx4 >= npt) return;
  float mem[4] = {0.0f, 0.0f, 0.0f, 0.0f};
#pragma unroll
  for (int t = 0; t < T_; ++t) {
    float y[4], sv[4];
    ld4(&Y[(size_t)t * npt + idx4], y);
#pragma unroll
    for (int j = 0; j < 4; ++j) {
      float m2 = mem[j] + (y[j] - mem[j]) * TAU_INV;
      float s = (m2 - V_TH >= 0.0f) ? 1.0f : 0.0f;
      sv[j] = s;
      mem[j] = (s != 0.0f) ? 0.0f : m2;
    }
    st4(&S[(size_t)t * npt + idx4], sv);
  }
}

// ---------------------------------------------------------------------------
// Linear attention per (t,b,h): kv = k^T v / N (64x64), y = q @ kv (1024x64).
// Spikes are {0,1}: kv entries are counts/1024 and y sums <=64 multiples of
// 2^-10 -> all arithmetic here is EXACT in fp32 regardless of order.
// ---------------------------------------------------------------------------
__global__ __launch_bounds__(256) void attn_kernel(
    const __hip_bfloat16* __restrict__ Q,
    const __hip_bfloat16* __restrict__ Kk,
    const __hip_bfloat16* __restrict__ V,
    float* __restrict__ Y)
{
  __shared__ float s1[64][65];
  __shared__ float s2[64][65];
  __shared__ float kv[64][65];
  const int tid = threadIdx.x;
  const int h = blockIdx.x, b = blockIdx.y, t = blockIdx.z;
  const size_t base = ((size_t)t * B_ + b) * (size_t)N_ * C_ + (size_t)h * D_;
  const int d0 = (tid >> 4) * 4;
  const int e0 = (tid & 15) * 4;

  float acc[4][4];
#pragma unroll
  for (int i = 0; i < 4; ++i)
#pragma unroll
    for (int j = 0; j < 4; ++j) acc[i][j] = 0.0f;

  for (int nc = 0; nc < N_; nc += 64) {
#pragma unroll
    for (int i = 0; i < 16; ++i) {
      int idx = tid + i * 256;
      int r = idx >> 6, c = idx & 63;
      s1[r][c] = __bfloat162float(Kk[base + (size_t)(nc + r) * C_ + c]);
      s2[r][c] = __bfloat162float(V[base + (size_t)(nc + r) * C_ + c]);
    }
    __syncthreads();
#pragma unroll
    for (int nn = 0; nn < 64; ++nn) {
      float a[4], bb[4];
#pragma unroll
      for (int i = 0; i < 4; ++i) a[i] = s1[nn][d0 + i];
#pragma unroll
      for (int j = 0; j < 4; ++j) bb[j] = s2[nn][e0 + j];
#pragma unroll
      for (int i = 0; i < 4; ++i)
#pragma unroll
        for (int j = 0; j < 4; ++j) acc[i][j] += a[i] * bb[j];
    }
    __syncthreads();
  }
#pragma unroll
  for (int i = 0; i < 4; ++i)
#pragma unroll
    for (int j = 0; j < 4; ++j)
      kv[d0 + i][e0 + j] = acc[i][j] * (1.0f / (float)N_);
  __syncthreads();

  for (int rc = 0; rc < N_; rc += 64) {
#pragma unroll
    for (int i = 0; i < 16; ++i) {
      int idx = tid + i * 256;
      int r = idx >> 6, c = idx & 63;
      s1[r][c] = __bfloat162float(Q[base + (size_t)(rc + r) * C_ + c]);
    }
    __syncthreads();
    float o[4][4];
#pragma unroll
    for (int i = 0; i < 4; ++i)
#pragma unroll
      for (int j = 0; j < 4; ++j) o[i][j] = 0.0f;
#pragma unroll
    for (int d = 0; d < 64; ++d) {
      float a[4], bb[4];
#pragma unroll
      for (int i = 0; i < 4; ++i) a[i] = s1[d0 + i][d];
#pragma unroll
      for (int j = 0; j < 4; ++j) bb[j] = kv[d][e0 + j];
#pragma unroll
      for (int i = 0; i < 4; ++i)
#pragma unroll
        for (int j = 0; j < 4; ++j) o[i][j] += a[i] * bb[j];
    }
#pragma unroll
    for (int i = 0; i < 4; ++i)
#pragma unroll
      for (int j = 0; j < 4; ++j)
        Y[base + (size_t)(rc + d0 + i) * C_ + e0 + j] = o[i][j];
    __syncthreads();
  }
}

extern "C" void kernel_launch(void* const* d_in, const int* in_sizes, int n_in,
                              void* d_out, int out_size, void* d_ws, size_t ws_size,
                              hipStream_t stream)
{
  const float* x   = (const float*)d_in[0];
  const float* Wq  = (const float*)d_in[1];
  const float* bq  = (const float*)d_in[2];
  const float* Wk  = (const float*)d_in[3];
  const float* bk  = (const float*)d_in[4];
  const float* Wv  = (const float*)d_in[5];
  const float* bv  = (const float*)d_in[6];
  const float* Wp  = (const float*)d_in[7];
  const float* bp  = (const float*)d_in[8];
  const float* bnp = (const float*)d_in[9];   // (4 layers, 4, C)
  float* out = (float*)d_out;

  char* ws = (char*)d_ws;
  const size_t nElem = (size_t)T_ * M_ * C_;   // 16,777,216
  float*          Y   = (float*)ws;          ws += nElem * sizeof(float);          // 67MB
  __hip_bfloat16* q_s = (__hip_bfloat16*)ws; ws += nElem * sizeof(__hip_bfloat16);
  __hip_bfloat16* k_s = (__hip_bfloat16*)ws; ws += nElem * sizeof(__hip_bfloat16);
  __hip_bfloat16* v_s = (__hip_bfloat16*)ws; ws += nElem * sizeof(__hip_bfloat16);
  __hip_bfloat16* a_s = (__hip_bfloat16*)ws; ws += nElem * sizeof(__hip_bfloat16);

  const dim3 gg(C_ / 256, MT_ / 128);      // (2, 256) = 512 blocks (2/CU)
  const unsigned lif_grid = (unsigned)(((size_t)M_ * C_ / 4 + 255) / 256);

  // q
  gemm_bn<float><<<gg, 256, 0, stream>>>(x, Wq, bq, bnp + 0 * 4 * C_, Y);
  lif_scan<__hip_bfloat16><<<lif_grid, 256, 0, stream>>>(Y, q_s);
  // k
  gemm_bn<float><<<gg, 256, 0, stream>>>(x, Wk, bk, bnp + 1 * 4 * C_, Y);
  lif_scan<__hip_bfloat16><<<lif_grid, 256, 0, stream>>>(Y, k_s);
  // v
  gemm_bn<float><<<gg, 256, 0, stream>>>(x, Wv, bv, bnp + 2 * 4 * C_, Y);
  lif_scan<__hip_bfloat16><<<lif_grid, 256, 0, stream>>>(Y, v_s);

  // attention (exact) -> Y, then attn_lif -> a_s
  attn_kernel<<<dim3(H_, B_, T_), 256, 0, stream>>>(q_s, k_s, v_s, Y);
  lif_scan<__hip_bfloat16><<<lif_grid, 256, 0, stream>>>(Y, a_s);

  // proj -> Y, then proj_lif -> out (fp32 spikes)
  gemm_bn<__hip_bfloat16><<<gg, 256, 0, stream>>>(a_s, Wp, bp, bnp + 3 * 4 * C_, Y);
  lif_scan<float><<<lif_grid, 256, 0, stream>>>(Y, out);
}

// Round 7
// 984.391 us; speedup vs baseline: 3.9008x; 1.1490x over previous
//
#include <hip/hip_runtime.h>
#include <hip/hip_bf16.h>

// Problem constants (fixed by setup_inputs)
constexpr int T_ = 4, B_ = 8, N_ = 1024, C_ = 512, H_ = 8, D_ = 64;
constexpr int M_ = 8192;             // rows per timestep
constexpr int MT_ = 32768;           // T*M
constexpr int K_ = 512;

#define TAU_INV 0.5f
#define V_TH    1.0f
#define BN_EPS  1e-5f

// ---- load 4 consecutive elements as float ---------------------------------
__device__ __forceinline__ void ld4(const float* p, float* d) {
  const float4 v = *(const float4*)p;
  d[0] = v.x; d[1] = v.y; d[2] = v.z; d[3] = v.w;
}
__device__ __forceinline__ void ld4(const __hip_bfloat16* p, float* d) {
  const ushort4 u = *(const ushort4*)p;
  d[0] = __bfloat162float(*(const __hip_bfloat16*)&u.x);
  d[1] = __bfloat162float(*(const __hip_bfloat16*)&u.y);
  d[2] = __bfloat162float(*(const __hip_bfloat16*)&u.z);
  d[3] = __bfloat162float(*(const __hip_bfloat16*)&u.w);
}
// ---- store 4 consecutive values -------------------------------------------
__device__ __forceinline__ void st4(__hip_bfloat16* p, const float* s) {
  ushort4 u;
  *(__hip_bfloat16*)&u.x = __float2bfloat16(s[0]);
  *(__hip_bfloat16*)&u.y = __float2bfloat16(s[1]);
  *(__hip_bfloat16*)&u.z = __float2bfloat16(s[2]);
  *(__hip_bfloat16*)&u.w = __float2bfloat16(s[3]);
  *(ushort4*)p = u;
}
__device__ __forceinline__ void st4(float* p, const float* s) {
  *(float4*)p = make_float4(s[0], s[1], s[2], s[3]);
}

// ---- async global->LDS, 16B per lane (HW scatters lane*16 from wave base) --
__device__ __forceinline__ void dma16(const void* g, void* l) {
  __builtin_amdgcn_global_load_lds(
      (const __attribute__((address_space(1))) unsigned int*)g,
      (__attribute__((address_space(3))) unsigned int*)l, 16, 0, 0);
}

// ---------------------------------------------------------------------------
// W transpose: Wt[w][k][d] = W[w][d][k]  (k-major rows for DMA staging).
// ---------------------------------------------------------------------------
struct WPtrs { const float* W[4]; };

__global__ __launch_bounds__(256) void transpose_w(WPtrs wp, float* __restrict__ Wt)
{
  __shared__ float tile[32][33];
  const int w = blockIdx.z;
  const float* __restrict__ W = wp.W[w];
  float* __restrict__ dst = Wt + (size_t)w * K_ * C_;
  const int k0 = blockIdx.x * 32, d0 = blockIdx.y * 32;
  const int tx = threadIdx.x, ty = threadIdx.y;   // 32 x 8
#pragma unroll
  for (int i = 0; i < 32; i += 8)
    tile[ty + i][tx] = W[(size_t)(d0 + ty + i) * K_ + k0 + tx];
  __syncthreads();
#pragma unroll
  for (int i = 0; i < 32; i += 8)
    dst[(size_t)(k0 + ty + i) * C_ + d0 + tx] = tile[tx][ty + i];
}

// ---------------------------------------------------------------------------
// x transpose: XT[k][m*4 + t] = x[t][m][k]   (k-major, t-interleaved rows).
// ---------------------------------------------------------------------------
__global__ __launch_bounds__(256) void transpose_x(
    const float* __restrict__ x, float* __restrict__ XT)
{
  __shared__ float tile[32][132];
  const int bk = blockIdx.x * 32, bm = blockIdx.y * 32;
  const int tx = threadIdx.x & 31, ty = threadIdx.x >> 5;   // 32 x 8
#pragma unroll
  for (int t = 0; t < T_; ++t)
#pragma unroll
    for (int i = 0; i < 4; ++i) {
      const int m = ty + 8 * i;
      tile[tx][m * 4 + t] = x[((size_t)t * M_ + bm + m) * K_ + bk + tx];
    }
  __syncthreads();
  const int k = threadIdx.x >> 3, q = threadIdx.x & 7;
#pragma unroll
  for (int u = 0; u < 4; ++u)
    st4(&XT[(size_t)(bk + k) * MT_ + bm * 4 + q * 16 + u * 4],
        &tile[k][q * 16 + u * 4]);
}

// ---------------------------------------------------------------------------
// Fused GEMM (+bias +BN +in-register multi-step LIF) -> spike tensor (T,M,C).
// BIT-EXACTNESS CONTRACT: each output's k-summation is a single fp32
// accumulator over k = 0..511 STRICTLY ASCENDING; bias/BN/LIF expressions are
// textually identical to all prior passing rounds (absmax 0.0). Only data
// MOVEMENT changed (DMA staging, pre-transposed operands).
//
// Tile: 128 "rows" x 256 cols where rows = (32 m) x (4 t interleaved:
// tile-row r -> m = r>>2, t = r&3). Thread (tx,ty) owns m in {ty, ty+16},
// all 4 t, 16 cols -> LIF runs in-register over acc index i (== t).
//
// Staging: pure global_load_lds 16B/lane from k-major XT / Wt. LDS unpadded:
//   As[kk][128]  (A-frag reads are 4-addr wave-broadcast: conflict-free)
//   Bs[kk][256]  (B-frag b128 reads: 2 words/bank = free)
// ---------------------------------------------------------------------------
template <typename TIn, typename TOut>
struct GArgs {
  const TIn* AT;             // [K][MT] t-interleaved k-major input
  const float* Wt[3];        // [K][C]
  const float* bias[3];
  const float* bn[3];
  TOut* S[3];                // (T, M, C) spikes
};

template <typename TIn, typename TOut>
__global__ __launch_bounds__(256, 2) void gemm_lif(GArgs<TIn, TOut> args)
{
  constexpr int BK = 32;
  constexpr bool BF = (sizeof(TIn) == 2);
  __shared__ __align__(16) TIn  As[BK * 128];
  __shared__ __align__(16) float Bs[BK * 256];

  const int z = blockIdx.z;
  const TIn*   __restrict__ AT   = args.AT;
  const float* __restrict__ Wt   = args.Wt[z];
  const float* __restrict__ bias = args.bias[z];
  const float* __restrict__ bnp  = args.bn[z];
  TOut*        __restrict__ S    = args.S[z];

  const int tid  = threadIdx.x;
  const int lane = tid & 63;
  const int wave = __builtin_amdgcn_readfirstlane(tid >> 6);
  const int tx = tid & 15, ty = tid >> 4;
  const int bm_m = blockIdx.y * 32;       // m-tile base
  const int bm4  = bm_m * 4;              // word base within a k-row of AT
  const int bn0  = blockIdx.x * 256;

  float acc[2][4][4][4];   // [m-grp g][col-grp h][i==t][col j]
#pragma unroll
  for (int g = 0; g < 2; ++g)
#pragma unroll
    for (int h = 0; h < 4; ++h)
#pragma unroll
      for (int i = 0; i < 4; ++i)
#pragma unroll
        for (int j = 0; j < 4; ++j) acc[g][h][i][j] = 0.0f;

  for (int k0 = 0; k0 < K_; k0 += BK) {
    // ---- DMA-stage A tile (BK x 128 elems) -------------------------------
    if constexpr (!BF) {
#pragma unroll
      for (int c = 0; c < 4; ++c) {
        const int ins = wave * 4 + c;                 // 0..15, 2 kk-rows each
        const int kk = ins * 2 + (lane >> 5);
        dma16(AT + (size_t)(k0 + kk) * MT_ + bm4 + (lane & 31) * 4,
              (void*)((float*)As + ins * 256));
      }
    } else {
#pragma unroll
      for (int c = 0; c < 2; ++c) {
        const int ins = wave * 2 + c;                 // 0..7, 4 kk-rows each
        const int kk = ins * 4 + (lane >> 4);
        dma16(AT + (size_t)(k0 + kk) * MT_ + bm4 + (lane & 15) * 8,
              (void*)((TIn*)As + ins * 512));
      }
    }
    // ---- DMA-stage B tile (BK x 256 floats) ------------------------------
#pragma unroll
    for (int c = 0; c < 8; ++c) {
      const int ins = wave * 8 + c;                   // 0..31, 1 kk-row each
      dma16(Wt + (size_t)(k0 + ins) * C_ + bn0 + lane * 4,
            (void*)(Bs + ins * 256));
    }
    __syncthreads();                                  // drains vmcnt

    // ---- hot loop: k strictly ascending ----------------------------------
#pragma unroll
    for (int kk = 0; kk < BK; ++kk) {
      float a[2][4], b[4][4];
#pragma unroll
      for (int g = 0; g < 2; ++g)
        ld4((const TIn*)As + kk * 128 + ty * 4 + 64 * g, a[g]);
#pragma unroll
      for (int h = 0; h < 4; ++h)
        ld4(Bs + kk * 256 + tx * 4 + 64 * h, b[h]);
#pragma unroll
      for (int g = 0; g < 2; ++g)
#pragma unroll
        for (int h = 0; h < 4; ++h)
#pragma unroll
          for (int i = 0; i < 4; ++i)
#pragma unroll
            for (int j = 0; j < 4; ++j)
              acc[g][h][i][j] += a[g][i] * b[h][j];
    }
    __syncthreads();
  }

  // ---- epilogue: bias -> BN -> in-register LIF over t (i) ----------------
#pragma unroll
  for (int h = 0; h < 4; ++h) {
    const int d = bn0 + tx * 4 + 64 * h;
    float bi[4], gg[4], be[4], mu[4], vv[4];
    ld4(&bias[d], bi);
    ld4(&bnp[d], gg);
    ld4(&bnp[C_ + d], be);
    ld4(&bnp[2 * C_ + d], mu);
    ld4(&bnp[3 * C_ + d], vv);
    float inv[4];
#pragma unroll
    for (int j = 0; j < 4; ++j) inv[j] = 1.0f / sqrtf(vv[j] + BN_EPS);
#pragma unroll
    for (int g = 0; g < 2; ++g) {
      const int m = bm_m + ty + 16 * g;
      float sv[4][4];                       // [t][j]
#pragma unroll
      for (int j = 0; j < 4; ++j) {
        float mm = 0.0f;
#pragma unroll
        for (int t = 0; t < 4; ++t) {
          float y = acc[g][h][t][j] + bi[j];
          y = (y - mu[j]) * inv[j] * gg[j] + be[j];
          float m2 = mm + (y - mm) * TAU_INV;
          float s = (m2 - V_TH >= 0.0f) ? 1.0f : 0.0f;
          sv[t][j] = s;
          mm = (s != 0.0f) ? 0.0f : m2;
        }
      }
#pragma unroll
      for (int t = 0; t < 4; ++t)
        st4(&S[((size_t)t * M_ + m) * C_ + d], sv[t]);
    }
  }
}

// ---------------------------------------------------------------------------
// LIF + transpose: Y (t,m,c) fp32 -> AT[c][m*4+t] bf16 (proj GEMM input).
// Identical LIF expressions (absmax 0.0 contract).
// ---------------------------------------------------------------------------
__global__ __launch_bounds__(256) void lif_T(
    const float* __restrict__ Y, __hip_bfloat16* __restrict__ AT)
{
  __shared__ __hip_bfloat16 lds[64][72];   // [c][(m&15)*4+t], 144B rows (16B mult)
  const int bm = blockIdx.x * 16, bc = blockIdx.y * 64;
  const int tid = threadIdx.x;
  const int mm = tid >> 4, c4 = (tid & 15) * 4;
  float mem[4] = {0.0f, 0.0f, 0.0f, 0.0f};
#pragma unroll
  for (int t = 0; t < T_; ++t) {
    float y[4];
    ld4(&Y[((size_t)t * M_ + bm + mm) * C_ + bc + c4], y);
#pragma unroll
    for (int j = 0; j < 4; ++j) {
      float m2 = mem[j] + (y[j] - mem[j]) * TAU_INV;
      float s = (m2 - V_TH >= 0.0f) ? 1.0f : 0.0f;
      lds[c4 + j][mm * 4 + t] = __float2bfloat16(s);
      mem[j] = (s != 0.0f) ? 0.0f : m2;
    }
  }
  __syncthreads();
  const int c = tid >> 2, q = tid & 3;
  *(uint4*)(AT + (size_t)(bc + c) * MT_ + bm * 4 + q * 16) =
      *(const uint4*)&lds[c][q * 16];
}

// ---------------------------------------------------------------------------
// Linear attention per (t,b,h): kv = k^T v / N (64x64), y = q @ kv (1024x64).
// Spikes are {0,1}: all arithmetic here is EXACT in fp32 regardless of order.
// ---------------------------------------------------------------------------
__global__ __launch_bounds__(256) void attn_kernel(
    const __hip_bfloat16* __restrict__ Q,
    const __hip_bfloat16* __restrict__ Kk,
    const __hip_bfloat16* __restrict__ V,
    float* __restrict__ Y)
{
  __shared__ float s1[64][65];
  __shared__ float s2[64][65];
  __shared__ float kv[64][65];
  const int tid = threadIdx.x;
  const int h = blockIdx.x, b = blockIdx.y, t = blockIdx.z;
  const size_t base = ((size_t)t * B_ + b) * (size_t)N_ * C_ + (size_t)h * D_;
  const int d0 = (tid >> 4) * 4;
  const int e0 = (tid & 15) * 4;

  float acc[4][4];
#pragma unroll
  for (int i = 0; i < 4; ++i)
#pragma unroll
    for (int j = 0; j < 4; ++j) acc[i][j] = 0.0f;

  for (int nc = 0; nc < N_; nc += 64) {
#pragma unroll
    for (int i = 0; i < 16; ++i) {
      int idx = tid + i * 256;
      int r = idx >> 6, c = idx & 63;
      s1[r][c] = __bfloat162float(Kk[base + (size_t)(nc + r) * C_ + c]);
      s2[r][c] = __bfloat162float(V[base + (size_t)(nc + r) * C_ + c]);
    }
    __syncthreads();
#pragma unroll
    for (int nn = 0; nn < 64; ++nn) {
      float a[4], bb[4];
#pragma unroll
      for (int i = 0; i < 4; ++i) a[i] = s1[nn][d0 + i];
#pragma unroll
      for (int j = 0; j < 4; ++j) bb[j] = s2[nn][e0 + j];
#pragma unroll
      for (int i = 0; i < 4; ++i)
#pragma unroll
        for (int j = 0; j < 4; ++j) acc[i][j] += a[i] * bb[j];
    }
    __syncthreads();
  }
#pragma unroll
  for (int i = 0; i < 4; ++i)
#pragma unroll
    for (int j = 0; j < 4; ++j)
      kv[d0 + i][e0 + j] = acc[i][j] * (1.0f / (float)N_);
  __syncthreads();

  for (int rc = 0; rc < N_; rc += 64) {
#pragma unroll
    for (int i = 0; i < 16; ++i) {
      int idx = tid + i * 256;
      int r = idx >> 6, c = idx & 63;
      s1[r][c] = __bfloat162float(Q[base + (size_t)(rc + r) * C_ + c]);
    }
    __syncthreads();
    float o[4][4];
#pragma unroll
    for (int i = 0; i < 4; ++i)
#pragma unroll
      for (int j = 0; j < 4; ++j) o[i][j] = 0.0f;
#pragma unroll
    for (int d = 0; d < 64; ++d) {
      float a[4], bb[4];
#pragma unroll
      for (int i = 0; i < 4; ++i) a[i] = s1[d0 + i][d];
#pragma unroll
      for (int j = 0; j < 4; ++j) bb[j] = kv[d][e0 + j];
#pragma unroll
      for (int i = 0; i < 4; ++i)
#pragma unroll
        for (int j = 0; j < 4; ++j) o[i][j] += a[i] * bb[j];
    }
#pragma unroll
    for (int i = 0; i < 4; ++i)
#pragma unroll
      for (int j = 0; j < 4; ++j)
        Y[base + (size_t)(rc + d0 + i) * C_ + e0 + j] = o[i][j];
    __syncthreads();
  }
}

extern "C" void kernel_launch(void* const* d_in, const int* in_sizes, int n_in,
                              void* d_out, int out_size, void* d_ws, size_t ws_size,
                              hipStream_t stream)
{
  const float* x   = (const float*)d_in[0];
  const float* Wq  = (const float*)d_in[1];
  const float* bq  = (const float*)d_in[2];
  const float* Wk  = (const float*)d_in[3];
  const float* bk  = (const float*)d_in[4];
  const float* Wv  = (const float*)d_in[5];
  const float* bv  = (const float*)d_in[6];
  const float* Wp  = (const float*)d_in[7];
  const float* bp  = (const float*)d_in[8];
  const float* bnp = (const float*)d_in[9];   // (4 layers, 4, C)
  float* out = (float*)d_out;

  char* ws = (char*)d_ws;
  float* XT = (float*)ws;  ws += (size_t)K_ * MT_ * sizeof(float);     // 64 MB
  float* Wt = (float*)ws;  ws += (size_t)4 * K_ * C_ * sizeof(float);  //  4 MB
  __hip_bfloat16* q_s = (__hip_bfloat16*)ws; ws += (size_t)MT_ * C_ * 2;
  __hip_bfloat16* k_s = (__hip_bfloat16*)ws; ws += (size_t)MT_ * C_ * 2;
  __hip_bfloat16* v_s = (__hip_bfloat16*)ws; ws += (size_t)MT_ * C_ * 2;
  float* Y = XT;               // alias: XT dead after qkv GEMMs
  __hip_bfloat16* aT = q_s;    // alias: q_s dead after attn; same size

  // ---- one-time per-launch transposes ------------------------------------
  WPtrs wp; wp.W[0] = Wq; wp.W[1] = Wk; wp.W[2] = Wv; wp.W[3] = Wp;
  transpose_w<<<dim3(K_ / 32, C_ / 32, 4), dim3(32, 8), 0, stream>>>(wp, Wt);
  transpose_x<<<dim3(K_ / 32, M_ / 32), 256, 0, stream>>>(x, XT);

  // ---- fused q,k,v GEMM+BN+LIF (one dispatch, z = weight) ----------------
  GArgs<float, __hip_bfloat16> qa;
  qa.AT = XT;
  qa.Wt[0] = Wt; qa.Wt[1] = Wt + (size_t)K_ * C_; qa.Wt[2] = Wt + (size_t)2 * K_ * C_;
  qa.bias[0] = bq; qa.bias[1] = bk; qa.bias[2] = bv;
  qa.bn[0] = bnp + 0 * 4 * C_;
  qa.bn[1] = bnp + 1 * 4 * C_;
  qa.bn[2] = bnp + 2 * 4 * C_;
  qa.S[0] = q_s; qa.S[1] = k_s; qa.S[2] = v_s;
  gemm_lif<float, __hip_bfloat16>
      <<<dim3(C_ / 256, M_ / 32, 3), 256, 0, stream>>>(qa);

  // ---- attention (exact) -> Y, then LIF+transpose -> aT ------------------
  attn_kernel<<<dim3(H_, B_, T_), 256, 0, stream>>>(q_s, k_s, v_s, Y);
  lif_T<<<dim3(M_ / 16, C_ / 64), 256, 0, stream>>>(Y, aT);

  // ---- proj GEMM+BN+LIF -> out (fp32 spikes) -----------------------------
  GArgs<__hip_bfloat16, float> pa;
  pa.AT = aT;
  pa.Wt[0] = Wt + (size_t)3 * K_ * C_;
  pa.bias[0] = bp;
  pa.bn[0] = bnp + 3 * 4 * C_;
  pa.S[0] = out;
  gemm_lif<__hip_bfloat16, float>
      <<<dim3(C_ / 256, M_ / 32, 1), 256, 0, stream>>>(pa);
}